// Round 11
// baseline (512.883 us; speedup 1.0000x reference)
//
#include <hip/hip_runtime.h>

#define NB 4
#define NN 10000
#define NE 320000
#define EPB 128
#define NPAIR (NE / EPB)          // 2500 tiles per batch
#define NTIL (NB * NPAIR)         // 10000 tiles
#define NBLK (2 * NTIL)           // 20000 blocks, kinds interleaved in groups of 8

typedef unsigned int uint;
typedef unsigned short ushort;
typedef __attribute__((ext_vector_type(8))) short short8;
typedef __attribute__((ext_vector_type(4))) float f32x4;

// d_ws layout (bytes). All tables are A-fragments for the transposed scheme:
//   A-frag: laneDim row = mt*16 + lm ; elem j -> k = kt*32 + (j>>2)*16 + la*4 + (j&3)
#define WS_W1T 0        // 8 mt * 64 frags * 16B = 8KB   (K=6 padded to 32)
#define WS_W2T 8192     // 32KB
#define WS_W3T 40960    // 32KB
#define WS_WVT 73728    // 12 mt * 64 frags = 12KB  (rows = o*3+c, K=18 pad 32)

static __device__ __forceinline__ ushort f2bf(float f) {
    uint u = __float_as_uint(f);
    u += 0x7fffu + ((u >> 16) & 1u);
    return (ushort)(u >> 16);
}
static __device__ __forceinline__ uint pack2(float a, float b) {
    return (uint)f2bf(a) | ((uint)f2bf(b) << 16);
}
static __device__ __forceinline__ uint cvtpk(float a, float b) {
    uint r;
    asm("v_cvt_pk_bf16_f32 %0, %1, %2" : "=v"(r) : "v"(a), "v"(b));
    return r;
}
static __device__ __forceinline__ short8 u4s8(uint4 v) {
    union { uint4 u; short8 s; } x; x.u = v; return x.s;
}
static __device__ __forceinline__ f32x4 MF(uint4 a, uint4 b, f32x4 c) {
    return __builtin_amdgcn_mfma_f32_16x16x32_bf16(u4s8(a), u4s8(b), c, 0, 0, 0);
}

// ---------------- prep: pack transposed weight fragment tables ----------------
__global__ void prep_kernel(const float* __restrict__ W1, const float* __restrict__ W2,
                            const float* __restrict__ W3, const float* __restrict__ Wv,
                            unsigned char* __restrict__ ws) {
    int tid = blockIdx.x * blockDim.x + threadIdx.x;
    if (tid < 4096) {
        const float* W = (tid < 2048) ? W2 : W3;
        uint4* dst = (uint4*)(ws + ((tid < 2048) ? WS_W2T : WS_W3T));
        int f = tid & 2047;                    // f = (mt*4 + kt)*64 + lane
        int lane = f & 63, kt = (f >> 6) & 3, mt = (f >> 8) & 7;
        int la = lane >> 4, lm = lane & 15;
        int n = mt * 16 + lm;
        uint w[4];
        #pragma unroll
        for (int jw = 0; jw < 4; ++jw) {
            int j0 = jw * 2, j1 = j0 + 1;
            int k0 = kt * 32 + (j0 >> 2) * 16 + la * 4 + (j0 & 3);
            int k1 = kt * 32 + (j1 >> 2) * 16 + la * 4 + (j1 & 3);
            w[jw] = pack2(W[n * 128 + k0], W[n * 128 + k1]);
        }
        dst[f] = make_uint4(w[0], w[1], w[2], w[3]);
    } else if (tid < 4608) {
        int f = tid - 4096;                    // f = mt*64 + lane, mt 0..7
        int lane = f & 63, mt = f >> 6;
        int la = lane >> 4, lm = lane & 15;
        int n = mt * 16 + lm;
        uint w[4];
        #pragma unroll
        for (int jw = 0; jw < 4; ++jw) {
            int j0 = jw * 2, j1 = j0 + 1;
            int k0 = (j0 >> 2) * 16 + la * 4 + (j0 & 3);
            int k1 = (j1 >> 2) * 16 + la * 4 + (j1 & 3);
            float f0 = (k0 < 6) ? W1[n * 6 + k0] : 0.f;
            float f1 = (k1 < 6) ? W1[n * 6 + k1] : 0.f;
            w[jw] = pack2(f0, f1);
        }
        ((uint4*)(ws + WS_W1T))[f] = make_uint4(w[0], w[1], w[2], w[3]);
    } else if (tid < 5376) {
        int f = tid - 4608;                    // f = mt*64 + lane, mt 0..11
        int lane = f & 63, mt = f >> 6;
        int la = lane >> 4, lm = lane & 15;
        int row = mt * 16 + lm;                // row = o*3 + c
        int o = row / 3, c = row - o * 3;
        uint w[4];
        #pragma unroll
        for (int jw = 0; jw < 4; ++jw) {
            float vv[2];
            #pragma unroll
            for (int dc = 0; dc < 2; ++dc) {
                int j = jw * 2 + dc;
                int k = (j >> 2) * 16 + la * 4 + (j & 3);
                int i = k / 3, cc = k - i * 3;
                vv[dc] = (k < 18 && cc == c) ? Wv[o * 6 + i] * (1.f / 3.f) : 0.f;
            }
            w[jw] = pack2(vv[0], vv[1]);
        }
        ((uint4*)(ws + WS_WVT))[f] = make_uint4(w[0], w[1], w[2], w[3]);
    }
}

// ---------------- main: mixed kinds; aout staged stores (r10-proven), vout direct (r9-proven) ----------------
__global__ __launch_bounds__(256, 3)
void edge_kernel(const float* __restrict__ pos0, const float* __restrict__ pos1,
                 const int* __restrict__ src, const int* __restrict__ dstI,
                 const float* __restrict__ b1, const float* __restrict__ b2,
                 const float* __restrict__ b3,
                 const unsigned char* __restrict__ ws, float* __restrict__ out) {
    __shared__ __align__(16) float smem[12416];   // 48.5 KB
    float* s_pts = smem;                 // [128][13]
    float* s_vn = smem + 1664;           // vout: s_vec [128][20] | aout: s_norm [6][128]
    float* s_stage = smem + 1664 + 2560; // 8192 dwords: aout 4 waves x 2048

    const int tid = threadIdx.x;
    const int lane = tid & 63;
    const int w = tid >> 6;
    const int lm = lane & 15;
    const int la = lane >> 4;
    const int ew0 = w * 32;
    const int el = ew0 + (lane & 31);
    const int side = lane >> 5;

    const int bid = blockIdx.x;
    const int kind = (bid >> 3) & 1;
    const int idx = ((bid >> 4) << 3) | (bid & 7);
    const int b = idx / NPAIR;
    const int e0 = (idx - b * NPAIR) * EPB;
    const size_t eg0 = (size_t)b * NE + e0;
    const f32x4 zero4 = {0.f, 0.f, 0.f, 0.f};

    // gather (wave-local slice, both pos arrays per lane)
    {
        const int node = side ? dstI[e0 + el] : src[e0 + el];
        const size_t pb = ((size_t)b * NN + node) * 3;
        s_pts[el * 13 + side * 3 + 0] = pos0[pb + 0];
        s_pts[el * 13 + side * 3 + 1] = pos0[pb + 1];
        s_pts[el * 13 + side * 3 + 2] = pos0[pb + 2];
        s_pts[el * 13 + 6 + side * 3 + 0] = pos1[pb + 0];
        s_pts[el * 13 + 6 + side * 3 + 1] = pos1[pb + 1];
        s_pts[el * 13 + 6 + side * 3 + 2] = pos1[pb + 2];
    }

    if (kind == 0) {
        // ================= v_out (direct stores — r9-proven path) =================
        {
            float P[12];
            #pragma unroll
            for (int i = 0; i < 12; ++i) P[i] = s_pts[el * 13 + i];
            if (side == 0) {
                const int va[4] = {1, 3, 2, 3}, vbx[4] = {0, 2, 0, 1};
                float v[4][3];
                #pragma unroll
                for (int i = 0; i < 4; ++i)
                    #pragma unroll
                    for (int c = 0; c < 3; ++c) v[i][c] = P[va[i] * 3 + c] - P[vbx[i] * 3 + c];
                float4 t0v = {v[0][0], v[0][1], v[0][2], v[1][0]};
                float4 t1v = {v[1][1], v[1][2], v[2][0], v[2][1]};
                float4 t2v = {v[2][2], v[3][0], v[3][1], v[3][2]};
                *(float4*)&s_vn[el * 20 + 0] = t0v;
                *(float4*)&s_vn[el * 20 + 4] = t1v;
                *(float4*)&s_vn[el * 20 + 8] = t2v;
            } else {
                float v4[3], v5[3];
                #pragma unroll
                for (int c = 0; c < 3; ++c) {
                    v4[c] = P[6 + c] - P[3 + c];   // p1s - p0d
                    v5[c] = P[9 + c] - P[0 + c];   // p1d - p0s
                }
                float4 tv4 = {v4[0], v4[1], v4[2], v5[0]};
                *(float4*)&s_vn[el * 20 + 12] = tv4;
                float2 tv2 = {v5[1], v5[2]};
                *(float2*)&s_vn[el * 20 + 16] = tv2;
            }
        }
        uint4 vbv[2];
        #pragma unroll
        for (int nt = 0; nt < 2; ++nt) {
            const int e = ew0 + nt * 16 + lm;
            float4 q = *(const float4*)&s_vn[e * 20 + la * 4];
            uint c2 = 0;
            if (la == 0) c2 = cvtpk(s_vn[e * 20 + 16], s_vn[e * 20 + 17]);
            vbv[nt] = make_uint4(cvtpk(q.x, q.y), cvtpk(q.z, q.w), c2, 0u);
        }
        const uint4* WVT = (const uint4*)(ws + WS_WVT);
        uint4 wv[12];
        #pragma unroll
        for (int mt = 0; mt < 12; ++mt) wv[mt] = WVT[mt * 64 + lane];
        float* voutP = out + (size_t)NB * NE * 128;
        #pragma unroll
        for (int mt = 0; mt < 12; ++mt)
            #pragma unroll
            for (int nt = 0; nt < 2; ++nt) {
                f32x4 av = MF(wv[mt], vbv[nt], zero4);
                const size_t e = eg0 + ew0 + nt * 16 + lm;
                *(f32x4*)&voutP[e * 192 + mt * 16 + la * 4] = av;
            }
        return;
    }

    // ================= a_out MLP (r10-proven path, staged contiguous stores) =================
    {
        float P[12];
        #pragma unroll
        for (int i = 0; i < 12; ++i) P[i] = s_pts[el * 13 + i];
        if (side == 0) {
            const int va[4] = {1, 3, 2, 3}, vbx[4] = {0, 2, 0, 1};
            #pragma unroll
            for (int i = 0; i < 4; ++i) {
                float x = P[va[i] * 3 + 0] - P[vbx[i] * 3 + 0];
                float y = P[va[i] * 3 + 1] - P[vbx[i] * 3 + 1];
                float z = P[va[i] * 3 + 2] - P[vbx[i] * 3 + 2];
                s_vn[i * 128 + el] = sqrtf(x * x + y * y + z * z);
            }
        } else {
            float x4 = P[6] - P[3], y4 = P[7] - P[4], z4 = P[8] - P[5];
            float x5 = P[9] - P[0], y5 = P[10] - P[1], z5 = P[11] - P[2];
            s_vn[4 * 128 + el] = sqrtf(x4 * x4 + y4 * y4 + z4 * z4);
            s_vn[5 * 128 + el] = sqrtf(x5 * x5 + y5 * y5 + z5 * z5);
        }
    }

    const uint4* W1T = (const uint4*)(ws + WS_W1T);
    const uint4* W2T = (const uint4*)(ws + WS_W2T);
    const uint4* W3T = (const uint4*)(ws + WS_W3T);

    // --- layer 1 ---
    f32x4 acc[8][2];
    {
        uint4 vb1[2];
        #pragma unroll
        for (int nt = 0; nt < 2; ++nt) {
            const int e = ew0 + nt * 16 + lm;
            uint c0 = 0, c1 = 0;
            if (la == 0) {
                c0 = cvtpk(s_vn[0 * 128 + e], s_vn[1 * 128 + e]);
                c1 = cvtpk(s_vn[2 * 128 + e], s_vn[3 * 128 + e]);
            } else if (la == 1) {
                c0 = cvtpk(s_vn[4 * 128 + e], s_vn[5 * 128 + e]);
            }
            vb1[nt] = make_uint4(c0, c1, 0u, 0u);
        }
        #pragma unroll
        for (int mt = 0; mt < 8; ++mt) {
            uint4 w1m = W1T[mt * 64 + lane];
            #pragma unroll
            for (int nt = 0; nt < 2; ++nt)
                acc[mt][nt] = MF(w1m, vb1[nt], zero4);
        }
    }
    uint4 vb[2][4];
    #pragma unroll
    for (int mt = 0; mt < 8; ++mt) {
        f32x4 bc = *(const f32x4*)&b1[mt * 16 + la * 4];
        #pragma unroll
        for (int nt = 0; nt < 2; ++nt)
            #pragma unroll
            for (int r = 0; r < 4; ++r) {
                float x = acc[mt][nt][r] + bc[r];
                acc[mt][nt][r] = fmaxf(x, 0.2f * x);
            }
    }
    #pragma unroll
    for (int nt = 0; nt < 2; ++nt)
        #pragma unroll
        for (int kt = 0; kt < 4; ++kt)
            vb[nt][kt] = make_uint4(
                cvtpk(acc[2*kt][nt][0], acc[2*kt][nt][1]),
                cvtpk(acc[2*kt][nt][2], acc[2*kt][nt][3]),
                cvtpk(acc[2*kt+1][nt][0], acc[2*kt+1][nt][1]),
                cvtpk(acc[2*kt+1][nt][2], acc[2*kt+1][nt][3]));

    // --- layer 2 (W2 from L2) ---
    #pragma unroll
    for (int mt = 0; mt < 8; ++mt)
        #pragma unroll
        for (int nt = 0; nt < 2; ++nt) acc[mt][nt] = zero4;
    #pragma unroll
    for (int kt = 0; kt < 4; ++kt) {
        uint4 wf[8];
        #pragma unroll
        for (int mt = 0; mt < 8; ++mt) wf[mt] = W2T[(mt * 4 + kt) * 64 + lane];
        #pragma unroll
        for (int mt = 0; mt < 8; ++mt)
            #pragma unroll
            for (int nt = 0; nt < 2; ++nt)
                acc[mt][nt] = MF(wf[mt], vb[nt][kt], acc[mt][nt]);
    }
    #pragma unroll
    for (int mt = 0; mt < 8; ++mt) {
        f32x4 bc = *(const f32x4*)&b2[mt * 16 + la * 4];
        #pragma unroll
        for (int nt = 0; nt < 2; ++nt)
            #pragma unroll
            for (int r = 0; r < 4; ++r) {
                float x = acc[mt][nt][r] + bc[r];
                acc[mt][nt][r] = fmaxf(x, 0.2f * x);
            }
    }
    #pragma unroll
    for (int nt = 0; nt < 2; ++nt)
        #pragma unroll
        for (int kt = 0; kt < 4; ++kt)
            vb[nt][kt] = make_uint4(
                cvtpk(acc[2*kt][nt][0], acc[2*kt][nt][1]),
                cvtpk(acc[2*kt][nt][2], acc[2*kt][nt][3]),
                cvtpk(acc[2*kt+1][nt][0], acc[2*kt+1][nt][1]),
                cvtpk(acc[2*kt+1][nt][2], acc[2*kt+1][nt][3]));

    // --- layer 3 (W3 from L2) ---
    #pragma unroll
    for (int mt = 0; mt < 8; ++mt)
        #pragma unroll
        for (int nt = 0; nt < 2; ++nt) acc[mt][nt] = zero4;
    #pragma unroll
    for (int kt = 0; kt < 4; ++kt) {
        uint4 wf[8];
        #pragma unroll
        for (int mt = 0; mt < 8; ++mt) wf[mt] = W3T[(mt * 4 + kt) * 64 + lane];
        #pragma unroll
        for (int mt = 0; mt < 8; ++mt)
            #pragma unroll
            for (int nt = 0; nt < 2; ++nt)
                acc[mt][nt] = MF(wf[mt], vb[nt][kt], acc[mt][nt]);
    }

    // --- bias3 + staged contiguous a_out stores (all 64 lanes write; uniform write-set) ---
    float* stg = s_stage + w * 2048;
    const int sw = (lm & 3) << 4;
    #pragma unroll
    for (int nt = 0; nt < 2; ++nt) {
        #pragma unroll
        for (int mt = 0; mt < 8; ++mt) {
            f32x4 bc = *(const f32x4*)&b3[mt * 16 + la * 4];
            f32x4 v = acc[mt][nt] + bc;
            *(f32x4*)&stg[lm * 128 + ((mt * 16 + la * 4) ^ sw)] = v;
        }
        // copyout: 8 x 1KB contiguous per wave
        float* gb = out + (eg0 + ew0 + nt * 16) * 128;
        #pragma unroll
        for (int i = 0; i < 8; ++i) {
            const int flat = i * 256 + lane * 4;
            const int r = flat >> 7;
            const int c = flat & 127;
            f32x4 v = *(const f32x4*)&stg[r * 128 + (c ^ ((r & 3) << 4))];
            *(f32x4*)&gb[flat] = v;
        }
    }
}

extern "C" void kernel_launch(void* const* d_in, const int* in_sizes, int n_in,
                              void* d_out, int out_size, void* d_ws, size_t ws_size,
                              hipStream_t stream) {
    const float* pos0 = (const float*)d_in[0];
    const float* pos1 = (const float*)d_in[1];
    const int* src = (const int*)d_in[2];
    const int* dstI = (const int*)d_in[3];
    const float* Wv = (const float*)d_in[4];
    const float* W1 = (const float*)d_in[5];
    const float* b1 = (const float*)d_in[6];
    const float* W2 = (const float*)d_in[7];
    const float* b2 = (const float*)d_in[8];
    const float* W3 = (const float*)d_in[9];
    const float* b3 = (const float*)d_in[10];
    unsigned char* ws = (unsigned char*)d_ws;
    float* out = (float*)d_out;

    prep_kernel<<<dim3(21), dim3(256), 0, stream>>>(W1, W2, W3, Wv, ws);
    edge_kernel<<<dim3(NBLK), dim3(256), 0, stream>>>(pos0, pos1, src, dstI, b1, b2, b3, ws, out);
}

// Round 12
// 497.257 us; speedup vs baseline: 1.0314x; 1.0314x over previous
//
#include <hip/hip_runtime.h>

#define NB 4
#define NN 10000
#define NE 320000
#define EPB 128
#define NPAIR (NE / EPB)          // 2500 tiles per batch
#define NBLK (2 * NB * NPAIR)     // 20000 blocks: even=v_out, odd=a_out (XCD-segregated)

typedef unsigned int uint;
typedef unsigned short ushort;
typedef __attribute__((ext_vector_type(8))) short short8;
typedef __attribute__((ext_vector_type(4))) float f32x4;

// d_ws layout (bytes). All tables are A-fragments for the transposed scheme:
//   A-frag: laneDim row = mt*16 + lm ; elem j -> k = kt*32 + (j>>2)*16 + la*4 + (j&3)
#define WS_W1T 0        // 8 mt * 64 frags * 16B = 8KB   (K=6 padded to 32)
#define WS_W2T 8192     // 32KB
#define WS_W3T 40960    // 32KB
#define WS_WVT 73728    // 12 mt * 64 frags = 12KB  (rows = o*3+c, K=18 pad 32)

static __device__ __forceinline__ ushort f2bf(float f) {
    uint u = __float_as_uint(f);
    u += 0x7fffu + ((u >> 16) & 1u);
    return (ushort)(u >> 16);
}
static __device__ __forceinline__ uint pack2(float a, float b) {
    return (uint)f2bf(a) | ((uint)f2bf(b) << 16);
}
static __device__ __forceinline__ uint cvtpk(float a, float b) {
    uint r;
    asm("v_cvt_pk_bf16_f32 %0, %1, %2" : "=v"(r) : "v"(a), "v"(b));
    return r;
}
static __device__ __forceinline__ short8 u4s8(uint4 v) {
    union { uint4 u; short8 s; } x; x.u = v; return x.s;
}
static __device__ __forceinline__ f32x4 MF(uint4 a, uint4 b, f32x4 c) {
    return __builtin_amdgcn_mfma_f32_16x16x32_bf16(u4s8(a), u4s8(b), c, 0, 0, 0);
}
// nontemporal 16B store (gfx950 'nt': no L2 allocate; stream via MC write-combine)
static __device__ __forceinline__ void stNT(float* p, f32x4 v) {
    __builtin_nontemporal_store(v, (f32x4*)p);
}

// ---------------- prep: pack transposed weight fragment tables ----------------
__global__ void prep_kernel(const float* __restrict__ W1, const float* __restrict__ W2,
                            const float* __restrict__ W3, const float* __restrict__ Wv,
                            unsigned char* __restrict__ ws) {
    int tid = blockIdx.x * blockDim.x + threadIdx.x;
    if (tid < 4096) {
        const float* W = (tid < 2048) ? W2 : W3;
        uint4* dst = (uint4*)(ws + ((tid < 2048) ? WS_W2T : WS_W3T));
        int f = tid & 2047;                    // f = (mt*4 + kt)*64 + lane
        int lane = f & 63, kt = (f >> 6) & 3, mt = (f >> 8) & 7;
        int la = lane >> 4, lm = lane & 15;
        int n = mt * 16 + lm;
        uint w[4];
        #pragma unroll
        for (int jw = 0; jw < 4; ++jw) {
            int j0 = jw * 2, j1 = j0 + 1;
            int k0 = kt * 32 + (j0 >> 2) * 16 + la * 4 + (j0 & 3);
            int k1 = kt * 32 + (j1 >> 2) * 16 + la * 4 + (j1 & 3);
            w[jw] = pack2(W[n * 128 + k0], W[n * 128 + k1]);
        }
        dst[f] = make_uint4(w[0], w[1], w[2], w[3]);
    } else if (tid < 4608) {
        int f = tid - 4096;                    // f = mt*64 + lane, mt 0..7
        int lane = f & 63, mt = f >> 6;
        int la = lane >> 4, lm = lane & 15;
        int n = mt * 16 + lm;
        uint w[4];
        #pragma unroll
        for (int jw = 0; jw < 4; ++jw) {
            int j0 = jw * 2, j1 = j0 + 1;
            int k0 = (j0 >> 2) * 16 + la * 4 + (j0 & 3);
            int k1 = (j1 >> 2) * 16 + la * 4 + (j1 & 3);
            float f0 = (k0 < 6) ? W1[n * 6 + k0] : 0.f;
            float f1 = (k1 < 6) ? W1[n * 6 + k1] : 0.f;
            w[jw] = pack2(f0, f1);
        }
        ((uint4*)(ws + WS_W1T))[f] = make_uint4(w[0], w[1], w[2], w[3]);
    } else if (tid < 5376) {
        int f = tid - 4608;                    // f = mt*64 + lane, mt 0..11
        int lane = f & 63, mt = f >> 6;
        int la = lane >> 4, lm = lane & 15;
        int row = mt * 16 + lm;                // row = o*3 + c
        int o = row / 3, c = row - o * 3;
        uint w[4];
        #pragma unroll
        for (int jw = 0; jw < 4; ++jw) {
            float vv[2];
            #pragma unroll
            for (int dc = 0; dc < 2; ++dc) {
                int j = jw * 2 + dc;
                int k = (j >> 2) * 16 + la * 4 + (j & 3);
                int i = k / 3, cc = k - i * 3;
                vv[dc] = (k < 18 && cc == c) ? Wv[o * 6 + i] * (1.f / 3.f) : 0.f;
            }
            w[jw] = pack2(vv[0], vv[1]);
        }
        ((uint4*)(ws + WS_WVT))[f] = make_uint4(w[0], w[1], w[2], w[3]);
    }
}

// ---------------- main: R5 structure verbatim + nontemporal output stores ----------------
// even bid: v_out streamer (zero barriers). odd bid: MLP -> a_out (one barrier).
// LDS overlay: [0,6656) s_pts both | [6656,...) vout: s_vecs (10.2KB)
//                                   | aout: s_norms (3KB) + s_W2 (32KB)
__global__ __launch_bounds__(256, 3)
void edge_kernel(const float* __restrict__ pos0, const float* __restrict__ pos1,
                 const int* __restrict__ src, const int* __restrict__ dstI,
                 const float* __restrict__ b1, const float* __restrict__ b2,
                 const float* __restrict__ b3,
                 const unsigned char* __restrict__ ws, float* __restrict__ out) {
    __shared__ __align__(16) char smem[42496];
    float (*s_pts)[13] = (float(*)[13])smem;

    const int tid = threadIdx.x;
    const int lane = tid & 63;
    const int w = tid >> 6;
    const int lm = lane & 15;
    const int la = lane >> 4;
    const int ew0 = w * 32;            // wave's local edge base
    const int el = ew0 + (lane & 31);
    const int side = lane >> 5;

    const int bid = blockIdx.x;
    const int kind = bid & 1;
    const int idx = bid >> 1;
    const int b = idx / NPAIR;
    const int e0 = (idx % NPAIR) * EPB;
    const size_t eg0 = (size_t)b * NE + e0;

    const f32x4 zero4 = {0.f, 0.f, 0.f, 0.f};

    // --- gather endpoints: lane covers (edge=lane&31, side); wave-local ---
    {
        const int e = e0 + el;
        const int node = side ? dstI[e] : src[e];
        const size_t pb = ((size_t)b * NN + node) * 3;
        float a0 = pos0[pb], a1 = pos0[pb + 1], a2 = pos0[pb + 2];
        float c0 = pos1[pb], c1 = pos1[pb + 1], c2 = pos1[pb + 2];
        s_pts[el][side * 3 + 0] = a0;
        s_pts[el][side * 3 + 1] = a1;
        s_pts[el][side * 3 + 2] = a2;
        s_pts[el][6 + side * 3 + 0] = c0;
        s_pts[el][6 + side * 3 + 1] = c1;
        s_pts[el][6 + side * 3 + 2] = c2;
    }

    if (kind == 0) {
        // ================= v_out streamer =================
        float (*s_vecs)[20] = (float(*)[20])(smem + 6656);
        {
            float P[12];
            #pragma unroll
            for (int i = 0; i < 12; ++i) P[i] = s_pts[el][i];
            if (side == 0) {
                const int va[4] = {1, 3, 2, 3}, vbx[4] = {0, 2, 0, 1};
                float v[4][3];
                #pragma unroll
                for (int i = 0; i < 4; ++i)
                    #pragma unroll
                    for (int c = 0; c < 3; ++c) v[i][c] = P[va[i] * 3 + c] - P[vbx[i] * 3 + c];
                float4 t0 = {v[0][0], v[0][1], v[0][2], v[1][0]};
                float4 t1 = {v[1][1], v[1][2], v[2][0], v[2][1]};
                float4 t2 = {v[2][2], v[3][0], v[3][1], v[3][2]};
                *(float4*)&s_vecs[el][0] = t0;
                *(float4*)&s_vecs[el][4] = t1;
                *(float4*)&s_vecs[el][8] = t2;
            } else {
                float v4[3], v5[3];
                #pragma unroll
                for (int c = 0; c < 3; ++c) {
                    v4[c] = P[6 + c] - P[3 + c];   // p1s - p0d
                    v5[c] = P[9 + c] - P[0 + c];   // p1d - p0s
                }
                float4 t = {v4[0], v4[1], v4[2], v5[0]};
                *(float4*)&s_vecs[el][12] = t;
                float2 t2 = {v5[1], v5[2]};
                *(float2*)&s_vecs[el][16] = t2;
            }
        }
        uint4 vbv[2];
        #pragma unroll
        for (int nt = 0; nt < 2; ++nt) {
            const int e = ew0 + nt * 16 + lm;
            float4 q = *(const float4*)&s_vecs[e][la * 4];
            uint c2 = 0;
            if (la == 0) c2 = cvtpk(s_vecs[e][16], s_vecs[e][17]);
            vbv[nt] = make_uint4(cvtpk(q.x, q.y), cvtpk(q.z, q.w), c2, 0u);
        }
        const uint4* WVT = (const uint4*)(ws + WS_WVT);
        uint4 wv[12];
        #pragma unroll
        for (int mt = 0; mt < 12; ++mt) wv[mt] = WVT[mt * 64 + lane];
        float* vout = out + (size_t)NB * NE * 128;
        #pragma unroll
        for (int mt = 0; mt < 12; ++mt)
            #pragma unroll
            for (int nt = 0; nt < 2; ++nt) {
                f32x4 av = MF(wv[mt], vbv[nt], zero4);
                const size_t e = eg0 + ew0 + nt * 16 + lm;
                stNT(&vout[e * 192 + mt * 16 + la * 4], av);
            }
        return;
    }

    // ================= a_out MLP =================
    float* s_normf = (float*)(smem + 6656);            // [6][128]
    uint4* s_W2 = (uint4*)(smem + 6656 + 3072);        // 2048 frags

    // stage W2 frag table into LDS (once per block; all waves cooperate)
    const uint4* W2T = (const uint4*)(ws + WS_W2T);
    {
        uint4 stg[8];
        #pragma unroll
        for (int it = 0; it < 8; ++it) stg[it] = W2T[it * 256 + tid];
        #pragma unroll
        for (int it = 0; it < 8; ++it) s_W2[it * 256 + tid] = stg[it];
    }

    // norms (wave-local)
    {
        float P[12];
        #pragma unroll
        for (int i = 0; i < 12; ++i) P[i] = s_pts[el][i];
        if (side == 0) {
            const int va[4] = {1, 3, 2, 3}, vbx[4] = {0, 2, 0, 1};
            #pragma unroll
            for (int i = 0; i < 4; ++i) {
                float x = P[va[i] * 3 + 0] - P[vbx[i] * 3 + 0];
                float y = P[va[i] * 3 + 1] - P[vbx[i] * 3 + 1];
                float z = P[va[i] * 3 + 2] - P[vbx[i] * 3 + 2];
                s_normf[i * 128 + el] = sqrtf(x * x + y * y + z * z);
            }
        } else {
            float x4 = P[6] - P[3], y4 = P[7] - P[4], z4 = P[8] - P[5];
            float x5 = P[9] - P[0], y5 = P[10] - P[1], z5 = P[11] - P[2];
            s_normf[4 * 128 + el] = sqrtf(x4 * x4 + y4 * y4 + z4 * z4);
            s_normf[5 * 128 + el] = sqrtf(x5 * x5 + y5 * y5 + z5 * z5);
        }
    }
    __syncthreads();   // staged W2 + all norms visible

    // --- layer 1 ---
    f32x4 acc[8][2];
    {
        uint4 vb1[2];
        #pragma unroll
        for (int nt = 0; nt < 2; ++nt) {
            const int e = ew0 + nt * 16 + lm;
            uint c0 = 0, c1 = 0;
            if (la == 0) {
                c0 = cvtpk(s_normf[0 * 128 + e], s_normf[1 * 128 + e]);
                c1 = cvtpk(s_normf[2 * 128 + e], s_normf[3 * 128 + e]);
            } else if (la == 1) {
                c0 = cvtpk(s_normf[4 * 128 + e], s_normf[5 * 128 + e]);
            }
            vb1[nt] = make_uint4(c0, c1, 0u, 0u);
        }
        const uint4* W1T = (const uint4*)(ws + WS_W1T);
        uint4 w1f[8];
        #pragma unroll
        for (int mt = 0; mt < 8; ++mt) w1f[mt] = W1T[mt * 64 + lane];
        #pragma unroll
        for (int mt = 0; mt < 8; ++mt)
            #pragma unroll
            for (int nt = 0; nt < 2; ++nt)
                acc[mt][nt] = MF(w1f[mt], vb1[nt], zero4);
    }
    uint4 vb[2][4];
    #pragma unroll
    for (int mt = 0; mt < 8; ++mt) {
        f32x4 bc = *(const f32x4*)&b1[mt * 16 + la * 4];
        #pragma unroll
        for (int nt = 0; nt < 2; ++nt)
            #pragma unroll
            for (int r = 0; r < 4; ++r) {
                float x = acc[mt][nt][r] + bc[r];
                acc[mt][nt][r] = fmaxf(x, 0.2f * x);
            }
    }
    #pragma unroll
    for (int nt = 0; nt < 2; ++nt)
        #pragma unroll
        for (int kt = 0; kt < 4; ++kt)
            vb[nt][kt] = make_uint4(
                cvtpk(acc[2*kt][nt][0], acc[2*kt][nt][1]),
                cvtpk(acc[2*kt][nt][2], acc[2*kt][nt][3]),
                cvtpk(acc[2*kt+1][nt][0], acc[2*kt+1][nt][1]),
                cvtpk(acc[2*kt+1][nt][2], acc[2*kt+1][nt][3]));

    // --- layer 2 (weights from LDS) ---
    #pragma unroll
    for (int mt = 0; mt < 8; ++mt)
        #pragma unroll
        for (int nt = 0; nt < 2; ++nt) acc[mt][nt] = zero4;
    #pragma unroll
    for (int kt = 0; kt < 4; ++kt) {
        uint4 wf[8];
        #pragma unroll
        for (int mt = 0; mt < 8; ++mt) wf[mt] = s_W2[(mt * 4 + kt) * 64 + lane];
        #pragma unroll
        for (int mt = 0; mt < 8; ++mt)
            #pragma unroll
            for (int nt = 0; nt < 2; ++nt)
                acc[mt][nt] = MF(wf[mt], vb[nt][kt], acc[mt][nt]);
    }
    #pragma unroll
    for (int mt = 0; mt < 8; ++mt) {
        f32x4 bc = *(const f32x4*)&b2[mt * 16 + la * 4];
        #pragma unroll
        for (int nt = 0; nt < 2; ++nt)
            #pragma unroll
            for (int r = 0; r < 4; ++r) {
                float x = acc[mt][nt][r] + bc[r];
                acc[mt][nt][r] = fmaxf(x, 0.2f * x);
            }
    }
    #pragma unroll
    for (int nt = 0; nt < 2; ++nt)
        #pragma unroll
        for (int kt = 0; kt < 4; ++kt)
            vb[nt][kt] = make_uint4(
                cvtpk(acc[2*kt][nt][0], acc[2*kt][nt][1]),
                cvtpk(acc[2*kt][nt][2], acc[2*kt][nt][3]),
                cvtpk(acc[2*kt+1][nt][0], acc[2*kt+1][nt][1]),
                cvtpk(acc[2*kt+1][nt][2], acc[2*kt+1][nt][3]));

    // --- layer 3 (weights from L2) ---
    const uint4* W3T = (const uint4*)(ws + WS_W3T);
    #pragma unroll
    for (int mt = 0; mt < 8; ++mt)
        #pragma unroll
        for (int nt = 0; nt < 2; ++nt) acc[mt][nt] = zero4;
    #pragma unroll
    for (int kt = 0; kt < 4; ++kt) {
        uint4 wf[8];
        #pragma unroll
        for (int mt = 0; mt < 8; ++mt) wf[mt] = W3T[(mt * 4 + kt) * 64 + lane];
        #pragma unroll
        for (int mt = 0; mt < 8; ++mt)
            #pragma unroll
            for (int nt = 0; nt < 2; ++nt)
                acc[mt][nt] = MF(wf[mt], vb[nt][kt], acc[mt][nt]);
    }
    // bias3 + direct nontemporal a_out stores
    #pragma unroll
    for (int mt = 0; mt < 8; ++mt) {
        f32x4 bc = *(const f32x4*)&b3[mt * 16 + la * 4];
        #pragma unroll
        for (int nt = 0; nt < 2; ++nt) {
            f32x4 v = acc[mt][nt] + bc;
            const size_t e = eg0 + ew0 + nt * 16 + lm;
            stNT(&out[e * 128 + mt * 16 + la * 4], v);
        }
    }
}

extern "C" void kernel_launch(void* const* d_in, const int* in_sizes, int n_in,
                              void* d_out, int out_size, void* d_ws, size_t ws_size,
                              hipStream_t stream) {
    const float* pos0 = (const float*)d_in[0];
    const float* pos1 = (const float*)d_in[1];
    const int* src = (const int*)d_in[2];
    const int* dstI = (const int*)d_in[3];
    const float* Wv = (const float*)d_in[4];
    const float* W1 = (const float*)d_in[5];
    const float* b1 = (const float*)d_in[6];
    const float* W2 = (const float*)d_in[7];
    const float* b2 = (const float*)d_in[8];
    const float* W3 = (const float*)d_in[9];
    const float* b3 = (const float*)d_in[10];
    unsigned char* ws = (unsigned char*)d_ws;
    float* out = (float*)d_out;

    prep_kernel<<<dim3(21), dim3(256), 0, stream>>>(W1, W2, W3, Wv, ws);
    edge_kernel<<<dim3(NBLK), dim3(256), 0, stream>>>(pos0, pos1, src, dstI, b1, b2, b3, ws, out);
}

// Round 13
// 419.124 us; speedup vs baseline: 1.2237x; 1.1864x over previous
//
#include <hip/hip_runtime.h>

#define NB 4
#define NN 10000
#define NE 320000
#define EPB 128
#define NPAIR (NE / EPB)          // 2500 tiles per batch
#define NBLK (2 * NB * NPAIR)     // 20000 blocks; kinds alternate per group of 8 (XCD-balanced)

typedef unsigned int uint;
typedef unsigned short ushort;
typedef __attribute__((ext_vector_type(8))) short short8;
typedef __attribute__((ext_vector_type(4))) float f32x4;

// d_ws layout (bytes). All tables are A-fragments for the transposed scheme:
//   A-frag: laneDim row = mt*16 + lm ; elem j -> k = kt*32 + (j>>2)*16 + la*4 + (j&3)
#define WS_W1T 0        // 8 mt * 64 frags * 16B = 8KB   (K=6 padded to 32)
#define WS_W2T 8192     // 32KB
#define WS_W3T 40960    // 32KB
#define WS_WVT 73728    // 12 mt * 64 frags = 12KB  (rows = o*3+c, K=18 pad 32)

static __device__ __forceinline__ ushort f2bf(float f) {
    uint u = __float_as_uint(f);
    u += 0x7fffu + ((u >> 16) & 1u);
    return (ushort)(u >> 16);
}
static __device__ __forceinline__ uint pack2(float a, float b) {
    return (uint)f2bf(a) | ((uint)f2bf(b) << 16);
}
static __device__ __forceinline__ uint cvtpk(float a, float b) {
    uint r;
    asm("v_cvt_pk_bf16_f32 %0, %1, %2" : "=v"(r) : "v"(a), "v"(b));
    return r;
}
static __device__ __forceinline__ short8 u4s8(uint4 v) {
    union { uint4 u; short8 s; } x; x.u = v; return x.s;
}
static __device__ __forceinline__ f32x4 MF(uint4 a, uint4 b, f32x4 c) {
    return __builtin_amdgcn_mfma_f32_16x16x32_bf16(u4s8(a), u4s8(b), c, 0, 0, 0);
}

// ---------------- prep: pack transposed weight fragment tables ----------------
__global__ void prep_kernel(const float* __restrict__ W1, const float* __restrict__ W2,
                            const float* __restrict__ W3, const float* __restrict__ Wv,
                            unsigned char* __restrict__ ws) {
    int tid = blockIdx.x * blockDim.x + threadIdx.x;
    if (tid < 4096) {
        const float* W = (tid < 2048) ? W2 : W3;
        uint4* dst = (uint4*)(ws + ((tid < 2048) ? WS_W2T : WS_W3T));
        int f = tid & 2047;                    // f = (mt*4 + kt)*64 + lane
        int lane = f & 63, kt = (f >> 6) & 3, mt = (f >> 8) & 7;
        int la = lane >> 4, lm = lane & 15;
        int n = mt * 16 + lm;
        uint w[4];
        #pragma unroll
        for (int jw = 0; jw < 4; ++jw) {
            int j0 = jw * 2, j1 = j0 + 1;
            int k0 = kt * 32 + (j0 >> 2) * 16 + la * 4 + (j0 & 3);
            int k1 = kt * 32 + (j1 >> 2) * 16 + la * 4 + (j1 & 3);
            w[jw] = pack2(W[n * 128 + k0], W[n * 128 + k1]);
        }
        dst[f] = make_uint4(w[0], w[1], w[2], w[3]);
    } else if (tid < 4608) {
        int f = tid - 4096;                    // f = mt*64 + lane, mt 0..7
        int lane = f & 63, mt = f >> 6;
        int la = lane >> 4, lm = lane & 15;
        int n = mt * 16 + lm;
        uint w[4];
        #pragma unroll
        for (int jw = 0; jw < 4; ++jw) {
            int j0 = jw * 2, j1 = j0 + 1;
            int k0 = (j0 >> 2) * 16 + la * 4 + (j0 & 3);
            int k1 = (j1 >> 2) * 16 + la * 4 + (j1 & 3);
            float f0 = (k0 < 6) ? W1[n * 6 + k0] : 0.f;
            float f1 = (k1 < 6) ? W1[n * 6 + k1] : 0.f;
            w[jw] = pack2(f0, f1);
        }
        ((uint4*)(ws + WS_W1T))[f] = make_uint4(w[0], w[1], w[2], w[3]);
    } else if (tid < 5376) {
        int f = tid - 4608;                    // f = mt*64 + lane, mt 0..11
        int lane = f & 63, mt = f >> 6;
        int la = lane >> 4, lm = lane & 15;
        int row = mt * 16 + lm;                // row = o*3 + c
        int o = row / 3, c = row - o * 3;
        uint w[4];
        #pragma unroll
        for (int jw = 0; jw < 4; ++jw) {
            float vv[2];
            #pragma unroll
            for (int dc = 0; dc < 2; ++dc) {
                int j = jw * 2 + dc;
                int k = (j >> 2) * 16 + la * 4 + (j & 3);
                int i = k / 3, cc = k - i * 3;
                vv[dc] = (k < 18 && cc == c) ? Wv[o * 6 + i] * (1.f / 3.f) : 0.f;
            }
            w[jw] = pack2(vv[0], vv[1]);
        }
        ((uint4*)(ws + WS_WVT))[f] = make_uint4(w[0], w[1], w[2], w[3]);
    }
}

// ---------------- main: R5 paths verbatim; ONLY the kind/idx mapping changed ----------------
// kind=(bid>>3)&1: with XCD=bid%8 round-robin, every XCD alternates vout/aout
// groups -> per-XCD output bytes balanced at ~205MB (was 245/164 segregated).
// idx=((bid>>4)<<3)|(bid&7): bijective onto [0,10000) per kind.
__global__ __launch_bounds__(256, 3)
void edge_kernel(const float* __restrict__ pos0, const float* __restrict__ pos1,
                 const int* __restrict__ src, const int* __restrict__ dstI,
                 const float* __restrict__ b1, const float* __restrict__ b2,
                 const float* __restrict__ b3,
                 const unsigned char* __restrict__ ws, float* __restrict__ out) {
    __shared__ __align__(16) char smem[42496];
    float (*s_pts)[13] = (float(*)[13])smem;

    const int tid = threadIdx.x;
    const int lane = tid & 63;
    const int w = tid >> 6;
    const int lm = lane & 15;
    const int la = lane >> 4;
    const int ew0 = w * 32;            // wave's local edge base
    const int el = ew0 + (lane & 31);
    const int side = lane >> 5;

    const int bid = blockIdx.x;
    const int kind = (bid >> 3) & 1;
    const int idx = ((bid >> 4) << 3) | (bid & 7);
    const int b = idx / NPAIR;
    const int e0 = (idx % NPAIR) * EPB;
    const size_t eg0 = (size_t)b * NE + e0;

    const f32x4 zero4 = {0.f, 0.f, 0.f, 0.f};

    // --- gather endpoints: lane covers (edge=lane&31, side); wave-local ---
    {
        const int e = e0 + el;
        const int node = side ? dstI[e] : src[e];
        const size_t pb = ((size_t)b * NN + node) * 3;
        float a0 = pos0[pb], a1 = pos0[pb + 1], a2 = pos0[pb + 2];
        float c0 = pos1[pb], c1 = pos1[pb + 1], c2 = pos1[pb + 2];
        s_pts[el][side * 3 + 0] = a0;
        s_pts[el][side * 3 + 1] = a1;
        s_pts[el][side * 3 + 2] = a2;
        s_pts[el][6 + side * 3 + 0] = c0;
        s_pts[el][6 + side * 3 + 1] = c1;
        s_pts[el][6 + side * 3 + 2] = c2;
    }

    if (kind == 0) {
        // ================= v_out streamer =================
        float (*s_vecs)[20] = (float(*)[20])(smem + 6656);
        {
            float P[12];
            #pragma unroll
            for (int i = 0; i < 12; ++i) P[i] = s_pts[el][i];
            if (side == 0) {
                const int va[4] = {1, 3, 2, 3}, vbx[4] = {0, 2, 0, 1};
                float v[4][3];
                #pragma unroll
                for (int i = 0; i < 4; ++i)
                    #pragma unroll
                    for (int c = 0; c < 3; ++c) v[i][c] = P[va[i] * 3 + c] - P[vbx[i] * 3 + c];
                float4 t0 = {v[0][0], v[0][1], v[0][2], v[1][0]};
                float4 t1 = {v[1][1], v[1][2], v[2][0], v[2][1]};
                float4 t2 = {v[2][2], v[3][0], v[3][1], v[3][2]};
                *(float4*)&s_vecs[el][0] = t0;
                *(float4*)&s_vecs[el][4] = t1;
                *(float4*)&s_vecs[el][8] = t2;
            } else {
                float v4[3], v5[3];
                #pragma unroll
                for (int c = 0; c < 3; ++c) {
                    v4[c] = P[6 + c] - P[3 + c];   // p1s - p0d
                    v5[c] = P[9 + c] - P[0 + c];   // p1d - p0s
                }
                float4 t = {v4[0], v4[1], v4[2], v5[0]};
                *(float4*)&s_vecs[el][12] = t;
                float2 t2 = {v5[1], v5[2]};
                *(float2*)&s_vecs[el][16] = t2;
            }
        }
        uint4 vbv[2];
        #pragma unroll
        for (int nt = 0; nt < 2; ++nt) {
            const int e = ew0 + nt * 16 + lm;
            float4 q = *(const float4*)&s_vecs[e][la * 4];
            uint c2 = 0;
            if (la == 0) c2 = cvtpk(s_vecs[e][16], s_vecs[e][17]);
            vbv[nt] = make_uint4(cvtpk(q.x, q.y), cvtpk(q.z, q.w), c2, 0u);
        }
        const uint4* WVT = (const uint4*)(ws + WS_WVT);
        uint4 wv[12];
        #pragma unroll
        for (int mt = 0; mt < 12; ++mt) wv[mt] = WVT[mt * 64 + lane];
        float* vout = out + (size_t)NB * NE * 128;
        #pragma unroll
        for (int mt = 0; mt < 12; ++mt)
            #pragma unroll
            for (int nt = 0; nt < 2; ++nt) {
                f32x4 av = MF(wv[mt], vbv[nt], zero4);
                const size_t e = eg0 + ew0 + nt * 16 + lm;
                *(f32x4*)&vout[e * 192 + mt * 16 + la * 4] = av;
            }
        return;
    }

    // ================= a_out MLP =================
    float* s_normf = (float*)(smem + 6656);            // [6][128]
    uint4* s_W2 = (uint4*)(smem + 6656 + 3072);        // 2048 frags

    // stage W2 frag table into LDS (once per block; all waves cooperate)
    const uint4* W2T = (const uint4*)(ws + WS_W2T);
    {
        uint4 stg[8];
        #pragma unroll
        for (int it = 0; it < 8; ++it) stg[it] = W2T[it * 256 + tid];
        #pragma unroll
        for (int it = 0; it < 8; ++it) s_W2[it * 256 + tid] = stg[it];
    }

    // norms (wave-local)
    {
        float P[12];
        #pragma unroll
        for (int i = 0; i < 12; ++i) P[i] = s_pts[el][i];
        if (side == 0) {
            const int va[4] = {1, 3, 2, 3}, vbx[4] = {0, 2, 0, 1};
            #pragma unroll
            for (int i = 0; i < 4; ++i) {
                float x = P[va[i] * 3 + 0] - P[vbx[i] * 3 + 0];
                float y = P[va[i] * 3 + 1] - P[vbx[i] * 3 + 1];
                float z = P[va[i] * 3 + 2] - P[vbx[i] * 3 + 2];
                s_normf[i * 128 + el] = sqrtf(x * x + y * y + z * z);
            }
        } else {
            float x4 = P[6] - P[3], y4 = P[7] - P[4], z4 = P[8] - P[5];
            float x5 = P[9] - P[0], y5 = P[10] - P[1], z5 = P[11] - P[2];
            s_normf[4 * 128 + el] = sqrtf(x4 * x4 + y4 * y4 + z4 * z4);
            s_normf[5 * 128 + el] = sqrtf(x5 * x5 + y5 * y5 + z5 * z5);
        }
    }
    __syncthreads();   // staged W2 + all norms visible

    // --- layer 1 ---
    f32x4 acc[8][2];
    {
        uint4 vb1[2];
        #pragma unroll
        for (int nt = 0; nt < 2; ++nt) {
            const int e = ew0 + nt * 16 + lm;
            uint c0 = 0, c1 = 0;
            if (la == 0) {
                c0 = cvtpk(s_normf[0 * 128 + e], s_normf[1 * 128 + e]);
                c1 = cvtpk(s_normf[2 * 128 + e], s_normf[3 * 128 + e]);
            } else if (la == 1) {
                c0 = cvtpk(s_normf[4 * 128 + e], s_normf[5 * 128 + e]);
            }
            vb1[nt] = make_uint4(c0, c1, 0u, 0u);
        }
        const uint4* W1T = (const uint4*)(ws + WS_W1T);
        uint4 w1f[8];
        #pragma unroll
        for (int mt = 0; mt < 8; ++mt) w1f[mt] = W1T[mt * 64 + lane];
        #pragma unroll
        for (int mt = 0; mt < 8; ++mt)
            #pragma unroll
            for (int nt = 0; nt < 2; ++nt)
                acc[mt][nt] = MF(w1f[mt], vb1[nt], zero4);
    }
    uint4 vb[2][4];
    #pragma unroll
    for (int mt = 0; mt < 8; ++mt) {
        f32x4 bc = *(const f32x4*)&b1[mt * 16 + la * 4];
        #pragma unroll
        for (int nt = 0; nt < 2; ++nt)
            #pragma unroll
            for (int r = 0; r < 4; ++r) {
                float x = acc[mt][nt][r] + bc[r];
                acc[mt][nt][r] = fmaxf(x, 0.2f * x);
            }
    }
    #pragma unroll
    for (int nt = 0; nt < 2; ++nt)
        #pragma unroll
        for (int kt = 0; kt < 4; ++kt)
            vb[nt][kt] = make_uint4(
                cvtpk(acc[2*kt][nt][0], acc[2*kt][nt][1]),
                cvtpk(acc[2*kt][nt][2], acc[2*kt][nt][3]),
                cvtpk(acc[2*kt+1][nt][0], acc[2*kt+1][nt][1]),
                cvtpk(acc[2*kt+1][nt][2], acc[2*kt+1][nt][3]));

    // --- layer 2 (weights from LDS) ---
    #pragma unroll
    for (int mt = 0; mt < 8; ++mt)
        #pragma unroll
        for (int nt = 0; nt < 2; ++nt) acc[mt][nt] = zero4;
    #pragma unroll
    for (int kt = 0; kt < 4; ++kt) {
        uint4 wf[8];
        #pragma unroll
        for (int mt = 0; mt < 8; ++mt) wf[mt] = s_W2[(mt * 4 + kt) * 64 + lane];
        #pragma unroll
        for (int mt = 0; mt < 8; ++mt)
            #pragma unroll
            for (int nt = 0; nt < 2; ++nt)
                acc[mt][nt] = MF(wf[mt], vb[nt][kt], acc[mt][nt]);
    }
    #pragma unroll
    for (int mt = 0; mt < 8; ++mt) {
        f32x4 bc = *(const f32x4*)&b2[mt * 16 + la * 4];
        #pragma unroll
        for (int nt = 0; nt < 2; ++nt)
            #pragma unroll
            for (int r = 0; r < 4; ++r) {
                float x = acc[mt][nt][r] + bc[r];
                acc[mt][nt][r] = fmaxf(x, 0.2f * x);
            }
    }
    #pragma unroll
    for (int nt = 0; nt < 2; ++nt)
        #pragma unroll
        for (int kt = 0; kt < 4; ++kt)
            vb[nt][kt] = make_uint4(
                cvtpk(acc[2*kt][nt][0], acc[2*kt][nt][1]),
                cvtpk(acc[2*kt][nt][2], acc[2*kt][nt][3]),
                cvtpk(acc[2*kt+1][nt][0], acc[2*kt+1][nt][1]),
                cvtpk(acc[2*kt+1][nt][2], acc[2*kt+1][nt][3]));

    // --- layer 3 (weights from L2) ---
    const uint4* W3T = (const uint4*)(ws + WS_W3T);
    #pragma unroll
    for (int mt = 0; mt < 8; ++mt)
        #pragma unroll
        for (int nt = 0; nt < 2; ++nt) acc[mt][nt] = zero4;
    #pragma unroll
    for (int kt = 0; kt < 4; ++kt) {
        uint4 wf[8];
        #pragma unroll
        for (int mt = 0; mt < 8; ++mt) wf[mt] = W3T[(mt * 4 + kt) * 64 + lane];
        #pragma unroll
        for (int mt = 0; mt < 8; ++mt)
            #pragma unroll
            for (int nt = 0; nt < 2; ++nt)
                acc[mt][nt] = MF(wf[mt], vb[nt][kt], acc[mt][nt]);
    }
    // bias3 + direct a_out stores
    #pragma unroll
    for (int mt = 0; mt < 8; ++mt) {
        f32x4 bc = *(const f32x4*)&b3[mt * 16 + la * 4];
        #pragma unroll
        for (int nt = 0; nt < 2; ++nt) {
            f32x4 v = acc[mt][nt] + bc;
            const size_t e = eg0 + ew0 + nt * 16 + lm;
            *(f32x4*)&out[e * 128 + mt * 16 + la * 4] = v;
        }
    }
}

extern "C" void kernel_launch(void* const* d_in, const int* in_sizes, int n_in,
                              void* d_out, int out_size, void* d_ws, size_t ws_size,
                              hipStream_t stream) {
    const float* pos0 = (const float*)d_in[0];
    const float* pos1 = (const float*)d_in[1];
    const int* src = (const int*)d_in[2];
    const int* dstI = (const int*)d_in[3];
    const float* Wv = (const float*)d_in[4];
    const float* W1 = (const float*)d_in[5];
    const float* b1 = (const float*)d_in[6];
    const float* W2 = (const float*)d_in[7];
    const float* b2 = (const float*)d_in[8];
    const float* W3 = (const float*)d_in[9];
    const float* b3 = (const float*)d_in[10];
    unsigned char* ws = (unsigned char*)d_ws;
    float* out = (float*)d_out;

    prep_kernel<<<dim3(21), dim3(256), 0, stream>>>(W1, W2, W3, Wv, ws);
    edge_kernel<<<dim3(NBLK), dim3(256), 0, stream>>>(pos0, pos1, src, dstI, b1, b2, b3, ws, out);
}